// Round 1
// baseline (294.515 us; speedup 1.0000x reference)
//
#include <hip/hip_runtime.h>
#include <hip/hip_bf16.h>
#include <stdint.h>
#include <stddef.h>

typedef __hip_bfloat16 bf16;
typedef __attribute__((ext_vector_type(4))) float f32x4;
typedef __attribute__((ext_vector_type(8))) short s16x8;

#define AS1 __attribute__((address_space(1)))
#define AS3 __attribute__((address_space(3)))

__device__ __forceinline__ void async_ld16(const void* g, void* l) {
  __builtin_amdgcn_global_load_lds((AS1 void*)g, (AS3 void*)l, 16, 0, 0);
}

// ---------------- conversions ----------------
__global__ __launch_bounds__(256) void f32_to_bf16_kernel(const float* __restrict__ src,
                                                          bf16* __restrict__ dst, int n) {
  int i = (blockIdx.x * 256 + threadIdx.x) * 8;
  if (i >= n) return;
  float4 a = *(const float4*)(src + i);
  float4 b = *(const float4*)(src + i + 4);
  bf16 t[8];
  t[0] = __float2bfloat16(a.x); t[1] = __float2bfloat16(a.y);
  t[2] = __float2bfloat16(a.z); t[3] = __float2bfloat16(a.w);
  t[4] = __float2bfloat16(b.x); t[5] = __float2bfloat16(b.y);
  t[6] = __float2bfloat16(b.z); t[7] = __float2bfloat16(b.w);
  *(s16x8*)(dst + i) = *(const s16x8*)t;
}

// ---------------- mask -> lengths (robust to u8 / int32 mask dtype) ----------------
// lengths in [1024,2048): an int32 mask's first 4096 BYTES are all zero (t<1024 valid),
// a u8 bool mask always has a 1 in its 4096 bytes (mask[b][2047]==1). So byte-OR over
// the first 4096 bytes disambiguates the element width.
__global__ __launch_bounds__(256) void lengths_kernel(const void* __restrict__ mask,
                                                      int* __restrict__ lengths) {
  __shared__ int s_any;
  __shared__ int s_cnt[256];
  const int tid = threadIdx.x;
  const int b = blockIdx.x;
  const unsigned char* m8 = (const unsigned char*)mask;
  if (tid == 0) s_any = 0;
  __syncthreads();
  int local = 0;
  for (int i = tid; i < 4096; i += 256) local |= m8[i];
  if (local) atomicOr(&s_any, 1);
  __syncthreads();
  int cnt = 0;
  if (s_any) {
    for (int t = tid; t < 2048; t += 256) cnt += (m8[b * 2048 + t] == 0) ? 1 : 0;
  } else {
    const int* m32 = (const int*)mask;
    for (int t = tid; t < 2048; t += 256) cnt += (m32[b * 2048 + t] == 0) ? 1 : 0;
  }
  s_cnt[tid] = cnt;
  __syncthreads();
  for (int s = 128; s > 0; s >>= 1) {
    if (tid < s) s_cnt[tid] += s_cnt[tid + s];
    __syncthreads();
  }
  if (tid == 0) lengths[b] = s_cnt[0];
}

// ---------------- 128x128 bf16 MFMA GEMM mainloop (C = A * B^T), K=1024 ----------------
// A: [M][1024] bf16 row-major, Bm: [N][1024] bf16 row-major. m97-proven layout:
// As/Bs [128][32] unpadded, global_load_lds width=16 staging, 16x16x32 bf16 MFMA.
__device__ __forceinline__ void gemm_mainloop(const bf16* __restrict__ A,
                                              const bf16* __restrict__ Bm,
                                              bf16* As, bf16* Bs,
                                              int m0, int n0, f32x4 (&acc)[4][4]) {
  const int K = 1024;
  const int tid = threadIdx.x;
  const int wave = tid >> 6, lane = tid & 63;
  const int col = lane & 15, quad = lane >> 4;
  const int wm = wave & 1, wn = wave >> 1;
#pragma unroll
  for (int mi = 0; mi < 4; mi++)
#pragma unroll
    for (int ni = 0; ni < 4; ni++) acc[mi][ni] = (f32x4){0.f, 0.f, 0.f, 0.f};

  // staging: 512 chunks of 16B per tile; wave w covers chunks [w*128, w*128+128)
  const int c0 = wave * 128 + lane;
  const int rowA0 = c0 >> 2, kc0 = (c0 & 3) * 8;
  const int c1 = c0 + 64;
  const int rowA1 = c1 >> 2, kc1 = (c1 & 3) * 8;
  char* ldsA0 = (char*)As + (size_t)(wave * 128) * 16;  // wave-uniform LDS base
  char* ldsA1 = ldsA0 + 64 * 16;
  char* ldsB0 = (char*)Bs + (size_t)(wave * 128) * 16;
  char* ldsB1 = ldsB0 + 64 * 16;
  const bf16* gA0 = A + (size_t)(m0 + rowA0) * K + kc0;
  const bf16* gA1 = A + (size_t)(m0 + rowA1) * K + kc1;
  const bf16* gB0 = Bm + (size_t)(n0 + rowA0) * K + kc0;
  const bf16* gB1 = Bm + (size_t)(n0 + rowA1) * K + kc1;

  for (int k0 = 0; k0 < K; k0 += 32) {
    async_ld16(gA0 + k0, ldsA0);
    async_ld16(gA1 + k0, ldsA1);
    async_ld16(gB0 + k0, ldsB0);
    async_ld16(gB1 + k0, ldsB1);
    __syncthreads();
    s16x8 af[4], bfr[4];
#pragma unroll
    for (int mi = 0; mi < 4; mi++)
      af[mi] = *(const s16x8*)(As + (wm * 64 + mi * 16 + col) * 32 + quad * 8);
#pragma unroll
    for (int ni = 0; ni < 4; ni++)
      bfr[ni] = *(const s16x8*)(Bs + (wn * 64 + ni * 16 + col) * 32 + quad * 8);
#pragma unroll
    for (int mi = 0; mi < 4; mi++)
#pragma unroll
      for (int ni = 0; ni < 4; ni++)
        acc[mi][ni] = __builtin_amdgcn_mfma_f32_16x16x32_bf16(af[mi], bfr[ni], acc[mi][ni], 0, 0, 0);
    __syncthreads();
  }
}

// ---------------- QKV projection: [4096,1024] @ [3072,1024]^T + b_in ----------------
// Epilogue scatters to Q/K [bh][t][64] (Q pre-scaled 0.125) and V transposed [bh][64][t].
__global__ __launch_bounds__(256) void gemm_qkv(const bf16* __restrict__ X,
                                                const bf16* __restrict__ W,
                                                const float* __restrict__ bias,
                                                bf16* __restrict__ Qd,
                                                bf16* __restrict__ Kd,
                                                bf16* __restrict__ Vt) {
  __shared__ bf16 As[128 * 32];
  __shared__ bf16 Bs[128 * 32];
  const int m0 = blockIdx.y * 128, n0 = blockIdx.x * 128;
  f32x4 acc[4][4];
  gemm_mainloop(X, W, As, Bs, m0, n0, acc);
  const int tid = threadIdx.x;
  const int wave = tid >> 6, lane = tid & 63;
  const int col = lane & 15, quad = lane >> 4;
  const int wm = wave & 1, wn = wave >> 1;
#pragma unroll
  for (int mi = 0; mi < 4; mi++)
#pragma unroll
    for (int ni = 0; ni < 4; ni++)
#pragma unroll
      for (int r = 0; r < 4; r++) {
        int m = m0 + wm * 64 + mi * 16 + quad * 4 + r;  // C/D: row = quad*4+reg
        int n = n0 + wn * 64 + ni * 16 + col;           //       col = lane&15
        float v = acc[mi][ni][r] + bias[n];
        int e = n & 1023, hh = e >> 6, d = e & 63;
        int t = m >> 1, b = m & 1;                      // m = t*B + b, B=2
        int bh = b * 16 + hh;
        if (n < 1024) {
          Qd[((size_t)bh * 2048 + t) * 64 + d] = __float2bfloat16(v * 0.125f);
        } else if (n < 2048) {
          Kd[((size_t)bh * 2048 + t) * 64 + d] = __float2bfloat16(v);
        } else {
          Vt[((size_t)bh * 64 + d) * 2048 + t] = __float2bfloat16(v);
        }
      }
}

// ---------------- flash attention: 64-row Q tile per block, 128-key tiles ----------------
__global__ __launch_bounds__(256) void attn_kernel(const bf16* __restrict__ Qd,
                                                   const bf16* __restrict__ Kd,
                                                   const bf16* __restrict__ Vt,
                                                   const int* __restrict__ lengths,
                                                   bf16* __restrict__ attn_out) {
  // padded rows (stride mult of 16B, not 0 mod 32 banks -> only free 2-way conflicts)
  __shared__ bf16 Qs[64 * 72];
  __shared__ bf16 Ks[128 * 72];
  __shared__ bf16 Vts[64 * 136];
  __shared__ bf16 Ps[64 * 136];

  const int bh = blockIdx.y;
  const int b = bh >> 4;
  const int h = bh & 15;
  const int qt0 = blockIdx.x * 64;
  const int tid = threadIdx.x;
  const int wave = tid >> 6, lane = tid & 63;
  const int col = lane & 15, quad = lane >> 4;
  const int len = lengths[b];
  const int nkt = (len + 127) >> 7;   // skip fully-masked key tiles

  // load Q tile (64 rows x 64 d), rows contiguous in global
  for (int i = tid; i < 512; i += 256) {
    int row = i >> 3, cc = i & 7;
    s16x8 v = *(const s16x8*)(Qd + ((size_t)bh * 2048 + qt0 + row) * 64 + cc * 8);
    *(s16x8*)(Qs + row * 72 + cc * 8) = v;
  }

  float m_run[4], l_run[4];
#pragma unroll
  for (int r = 0; r < 4; r++) { m_run[r] = -1e30f; l_run[r] = 0.f; }
  f32x4 oacc[4];
#pragma unroll
  for (int d = 0; d < 4; d++) oacc[d] = (f32x4){0.f, 0.f, 0.f, 0.f};

  for (int kt = 0; kt < nkt; kt++) {
    const int s0g = kt * 128;
    for (int i = tid; i < 1024; i += 256) {
      int row = i >> 3, cc = i & 7;
      s16x8 v = *(const s16x8*)(Kd + ((size_t)bh * 2048 + s0g + row) * 64 + cc * 8);
      *(s16x8*)(Ks + row * 72 + cc * 8) = v;
    }
    for (int i = tid; i < 1024; i += 256) {
      int row = i >> 4, cc = i & 15;
      s16x8 v = *(const s16x8*)(Vt + ((size_t)bh * 64 + row) * 2048 + s0g + cc * 8);
      *(s16x8*)(Vts + row * 136 + cc * 8) = v;
    }
    __syncthreads();

    // S = Q K^T for this wave's 16-row strip; wave owns rows [wave*16, wave*16+16)
    f32x4 sacc[8];
#pragma unroll
    for (int ni = 0; ni < 8; ni++) sacc[ni] = (f32x4){0.f, 0.f, 0.f, 0.f};
#pragma unroll
    for (int kh = 0; kh < 2; kh++) {
      s16x8 af = *(const s16x8*)(Qs + (wave * 16 + col) * 72 + kh * 32 + quad * 8);
#pragma unroll
      for (int ni = 0; ni < 8; ni++) {
        s16x8 bfr = *(const s16x8*)(Ks + (ni * 16 + col) * 72 + kh * 32 + quad * 8);
        sacc[ni] = __builtin_amdgcn_mfma_f32_16x16x32_bf16(af, bfr, sacc[ni], 0, 0, 0);
      }
    }

    // mask + online softmax. Lane owns rows quad*4+r at column ni*16+col.
#pragma unroll
    for (int r = 0; r < 4; r++) {
      float mx = -1e30f;
#pragma unroll
      for (int ni = 0; ni < 8; ni++) {
        float v = sacc[ni][r];
        if (s0g + ni * 16 + col >= len) v = -1e30f;
        sacc[ni][r] = v;
        mx = fmaxf(mx, v);
      }
      mx = fmaxf(mx, __shfl_xor(mx, 1, 64));
      mx = fmaxf(mx, __shfl_xor(mx, 2, 64));
      mx = fmaxf(mx, __shfl_xor(mx, 4, 64));
      mx = fmaxf(mx, __shfl_xor(mx, 8, 64));
      float m_new = fmaxf(m_run[r], mx);
      float alpha = __expf(m_run[r] - m_new);
      m_run[r] = m_new;
      float sum = 0.f;
#pragma unroll
      for (int ni = 0; ni < 8; ni++) {
        float p = __expf(sacc[ni][r] - m_new);
        sacc[ni][r] = p;
        sum += p;
      }
      sum += __shfl_xor(sum, 1, 64);
      sum += __shfl_xor(sum, 2, 64);
      sum += __shfl_xor(sum, 4, 64);
      sum += __shfl_xor(sum, 8, 64);
      l_run[r] = l_run[r] * alpha + sum;
#pragma unroll
      for (int d = 0; d < 4; d++) oacc[d][r] *= alpha;
      // P -> LDS (C-layout -> A-layout round-trip); wave writes only its own strip
#pragma unroll
      for (int ni = 0; ni < 8; ni++)
        Ps[(wave * 16 + quad * 4 + r) * 136 + ni * 16 + col] = __float2bfloat16(sacc[ni][r]);
    }

    // O += P V   (A = P rows from own strip, B = Vt rows = output d columns)
#pragma unroll
    for (int sk = 0; sk < 4; sk++) {
      s16x8 af = *(const s16x8*)(Ps + (wave * 16 + col) * 136 + sk * 32 + quad * 8);
#pragma unroll
      for (int d = 0; d < 4; d++) {
        s16x8 bfr = *(const s16x8*)(Vts + (d * 16 + col) * 136 + sk * 32 + quad * 8);
        oacc[d] = __builtin_amdgcn_mfma_f32_16x16x32_bf16(af, bfr, oacc[d], 0, 0, 0);
      }
    }
    __syncthreads();  // protect Ks/Vts restage
  }

  // epilogue: O / l -> attn_out[(t*2+b)*1024 + h*64 + d]
#pragma unroll
  for (int d = 0; d < 4; d++) {
#pragma unroll
    for (int r = 0; r < 4; r++) {
      int t = qt0 + wave * 16 + quad * 4 + r;
      float v = oacc[d][r] / l_run[r];
      attn_out[((size_t)t * 2 + b) * 1024 + h * 64 + d * 16 + col] = __float2bfloat16(v);
    }
  }
}

// ---------------- output projection: [4096,1024] @ [1024,1024]^T + b_out (fp32 out) --------
__global__ __launch_bounds__(256) void gemm_out(const bf16* __restrict__ Aa,
                                                const bf16* __restrict__ W,
                                                const float* __restrict__ bias,
                                                float* __restrict__ out) {
  __shared__ bf16 As[128 * 32];
  __shared__ bf16 Bs[128 * 32];
  const int m0 = blockIdx.y * 128, n0 = blockIdx.x * 128;
  f32x4 acc[4][4];
  gemm_mainloop(Aa, W, As, Bs, m0, n0, acc);
  const int tid = threadIdx.x;
  const int wave = tid >> 6, lane = tid & 63;
  const int col = lane & 15, quad = lane >> 4;
  const int wm = wave & 1, wn = wave >> 1;
#pragma unroll
  for (int mi = 0; mi < 4; mi++)
#pragma unroll
    for (int ni = 0; ni < 4; ni++)
#pragma unroll
      for (int r = 0; r < 4; r++) {
        int m = m0 + wm * 64 + mi * 16 + quad * 4 + r;
        int n = n0 + wn * 64 + ni * 16 + col;
        out[(size_t)m * 1024 + n] = acc[mi][ni][r] + bias[n];
      }
}

// ---------------- launch ----------------
extern "C" void kernel_launch(void* const* d_in, const int* in_sizes, int n_in,
                              void* d_out, int out_size, void* d_ws, size_t ws_size,
                              hipStream_t stream) {
  (void)in_sizes; (void)n_in; (void)out_size; (void)ws_size;
  const float* query = (const float*)d_in[0];
  const void*  mask  = d_in[1];
  const float* W_in  = (const float*)d_in[2];
  const float* b_in  = (const float*)d_in[3];
  const float* W_out = (const float*)d_in[4];
  const float* b_out = (const float*)d_in[5];
  float* out = (float*)d_out;

  char* ws = (char*)d_ws;
  // Xbf region reused as attn_out after QKV GEMM; Winbf region reused for Woutbf.
  bf16* Xbf    = (bf16*)(ws);                       // 8 MB  [4096][1024]
  bf16* attnb  = (bf16*)(ws);                       // alias (dead Xbf)
  bf16* Winbf  = (bf16*)(ws + 8388608);             // 6 MB  [3072][1024]
  bf16* Woutbf = (bf16*)(ws + 8388608);             // alias (dead Winbf), 2 MB
  bf16* Qd     = (bf16*)(ws + 14680064);            // 8 MB  [32][2048][64]
  bf16* Kd     = (bf16*)(ws + 23068672);            // 8 MB  [32][2048][64]
  bf16* Vt     = (bf16*)(ws + 31457280);            // 8 MB  [32][64][2048]
  int*  lens   = (int*)(ws + 39845888);

  lengths_kernel<<<2, 256, 0, stream>>>(mask, lens);
  f32_to_bf16_kernel<<<2048, 256, 0, stream>>>(query, Xbf, 4194304);
  f32_to_bf16_kernel<<<1536, 256, 0, stream>>>(W_in, Winbf, 3145728);
  gemm_qkv<<<dim3(24, 32), 256, 0, stream>>>(Xbf, Winbf, b_in, Qd, Kd, Vt);
  f32_to_bf16_kernel<<<512, 256, 0, stream>>>(W_out, Woutbf, 1048576);
  attn_kernel<<<dim3(32, 32), 256, 0, stream>>>(Qd, Kd, Vt, lens, attnb);
  gemm_out<<<dim3(8, 32), 256, 0, stream>>>(attnb, Woutbf, b_out, out);
}

// Round 2
// 227.931 us; speedup vs baseline: 1.2921x; 1.2921x over previous
//
#include <hip/hip_runtime.h>
#include <hip/hip_bf16.h>
#include <stdint.h>
#include <stddef.h>

typedef __hip_bfloat16 bf16;
typedef __attribute__((ext_vector_type(4))) float f32x4;
typedef __attribute__((ext_vector_type(8))) short s16x8;

#define AS1 __attribute__((address_space(1)))
#define AS3 __attribute__((address_space(3)))

__device__ __forceinline__ void async_ld16(const void* g, void* l) {
  __builtin_amdgcn_global_load_lds((AS1 void*)g, (AS3 void*)l, 16, 0, 0);
}

// ---------------- conversions ----------------
__global__ __launch_bounds__(256) void f32_to_bf16_kernel(const float* __restrict__ src,
                                                          bf16* __restrict__ dst, int n) {
  int i = (blockIdx.x * 256 + threadIdx.x) * 8;
  if (i >= n) return;
  float4 a = *(const float4*)(src + i);
  float4 b = *(const float4*)(src + i + 4);
  bf16 t[8];
  t[0] = __float2bfloat16(a.x); t[1] = __float2bfloat16(a.y);
  t[2] = __float2bfloat16(a.z); t[3] = __float2bfloat16(a.w);
  t[4] = __float2bfloat16(b.x); t[5] = __float2bfloat16(b.y);
  t[6] = __float2bfloat16(b.z); t[7] = __float2bfloat16(b.w);
  *(s16x8*)(dst + i) = *(const s16x8*)t;
}

// ---------------- mask -> lengths (robust to u8 / int32 mask dtype) ----------------
__global__ __launch_bounds__(256) void lengths_kernel(const void* __restrict__ mask,
                                                      int* __restrict__ lengths) {
  __shared__ int s_any;
  __shared__ int s_cnt[256];
  const int tid = threadIdx.x;
  const int b = blockIdx.x;
  const unsigned char* m8 = (const unsigned char*)mask;
  if (tid == 0) s_any = 0;
  __syncthreads();
  int local = 0;
  for (int i = tid; i < 4096; i += 256) local |= m8[i];
  if (local) atomicOr(&s_any, 1);
  __syncthreads();
  int cnt = 0;
  if (s_any) {
    for (int t = tid; t < 2048; t += 256) cnt += (m8[b * 2048 + t] == 0) ? 1 : 0;
  } else {
    const int* m32 = (const int*)mask;
    for (int t = tid; t < 2048; t += 256) cnt += (m32[b * 2048 + t] == 0) ? 1 : 0;
  }
  s_cnt[tid] = cnt;
  __syncthreads();
  for (int s = 128; s > 0; s >>= 1) {
    if (tid < s) s_cnt[tid] += s_cnt[tid + s];
    __syncthreads();
  }
  if (tid == 0) lengths[b] = s_cnt[0];
}

// ---------------- 128x128 bf16 MFMA GEMM mainloop (C = A * B^T), K=1024 ----------------
__device__ __forceinline__ void gemm_mainloop(const bf16* __restrict__ A,
                                              const bf16* __restrict__ Bm,
                                              bf16* As, bf16* Bs,
                                              int m0, int n0, f32x4 (&acc)[4][4]) {
  const int K = 1024;
  const int tid = threadIdx.x;
  const int wave = tid >> 6, lane = tid & 63;
  const int col = lane & 15, quad = lane >> 4;
  const int wm = wave & 1, wn = wave >> 1;
#pragma unroll
  for (int mi = 0; mi < 4; mi++)
#pragma unroll
    for (int ni = 0; ni < 4; ni++) acc[mi][ni] = (f32x4){0.f, 0.f, 0.f, 0.f};

  const int c0 = wave * 128 + lane;
  const int rowA0 = c0 >> 2, kc0 = (c0 & 3) * 8;
  const int c1 = c0 + 64;
  const int rowA1 = c1 >> 2, kc1 = (c1 & 3) * 8;
  char* ldsA0 = (char*)As + (size_t)(wave * 128) * 16;
  char* ldsA1 = ldsA0 + 64 * 16;
  char* ldsB0 = (char*)Bs + (size_t)(wave * 128) * 16;
  char* ldsB1 = ldsB0 + 64 * 16;
  const bf16* gA0 = A + (size_t)(m0 + rowA0) * K + kc0;
  const bf16* gA1 = A + (size_t)(m0 + rowA1) * K + kc1;
  const bf16* gB0 = Bm + (size_t)(n0 + rowA0) * K + kc0;
  const bf16* gB1 = Bm + (size_t)(n0 + rowA1) * K + kc1;

  for (int k0 = 0; k0 < K; k0 += 32) {
    async_ld16(gA0 + k0, ldsA0);
    async_ld16(gA1 + k0, ldsA1);
    async_ld16(gB0 + k0, ldsB0);
    async_ld16(gB1 + k0, ldsB1);
    __syncthreads();
    s16x8 af[4], bfr[4];
#pragma unroll
    for (int mi = 0; mi < 4; mi++)
      af[mi] = *(const s16x8*)(As + (wm * 64 + mi * 16 + col) * 32 + quad * 8);
#pragma unroll
    for (int ni = 0; ni < 4; ni++)
      bfr[ni] = *(const s16x8*)(Bs + (wn * 64 + ni * 16 + col) * 32 + quad * 8);
#pragma unroll
    for (int mi = 0; mi < 4; mi++)
#pragma unroll
      for (int ni = 0; ni < 4; ni++)
        acc[mi][ni] = __builtin_amdgcn_mfma_f32_16x16x32_bf16(af[mi], bfr[ni], acc[mi][ni], 0, 0, 0);
    __syncthreads();
  }
}

// ---------------- QKV projection: [4096,1024] @ [3072,1024]^T + b_in ----------------
// Q pre-scaled by SCALING*log2(e) so attention softmax runs in exp2 domain.
__global__ __launch_bounds__(256) void gemm_qkv(const bf16* __restrict__ X,
                                                const bf16* __restrict__ W,
                                                const float* __restrict__ bias,
                                                bf16* __restrict__ Qd,
                                                bf16* __restrict__ Kd,
                                                bf16* __restrict__ Vt) {
  __shared__ bf16 As[128 * 32];
  __shared__ bf16 Bs[128 * 32];
  const int m0 = blockIdx.y * 128, n0 = blockIdx.x * 128;
  f32x4 acc[4][4];
  gemm_mainloop(X, W, As, Bs, m0, n0, acc);
  const int tid = threadIdx.x;
  const int wave = tid >> 6, lane = tid & 63;
  const int col = lane & 15, quad = lane >> 4;
  const int wm = wave & 1, wn = wave >> 1;
  const float QSCALE = 0.125f * 1.4426950408889634f;
#pragma unroll
  for (int mi = 0; mi < 4; mi++)
#pragma unroll
    for (int ni = 0; ni < 4; ni++)
#pragma unroll
      for (int r = 0; r < 4; r++) {
        int m = m0 + wm * 64 + mi * 16 + quad * 4 + r;
        int n = n0 + wn * 64 + ni * 16 + col;
        float v = acc[mi][ni][r] + bias[n];
        int e = n & 1023, hh = e >> 6, d = e & 63;
        int t = m >> 1, b = m & 1;
        int bh = b * 16 + hh;
        if (n < 1024) {
          Qd[((size_t)bh * 2048 + t) * 64 + d] = __float2bfloat16(v * QSCALE);
        } else if (n < 2048) {
          Kd[((size_t)bh * 2048 + t) * 64 + d] = __float2bfloat16(v);
        } else {
          Vt[((size_t)bh * 64 + d) * 2048 + t] = __float2bfloat16(v);
        }
      }
}

// ---------------- flash attention v2: S^T form, async swizzled staging ----------------
// Block: 64 q rows (4 waves x 16), 64-key tiles, double-buffered K/V, 1 barrier/tile.
// S^T = K.Q^T via MFMA(A=K, B=Q): C col = q (lane&15), row = s (quad*4+r) -> mask is
// reg/quad-indexed, softmax state per-column, reductions need only 2 shuffles.
__global__ __launch_bounds__(256, 4) void attn_kernel(const bf16* __restrict__ Qd,
                                                      const bf16* __restrict__ Kd,
                                                      const bf16* __restrict__ Vt,
                                                      const int* __restrict__ lengths,
                                                      bf16* __restrict__ attn_out) {
  // All tiles 64x64 bf16, XOR-chunk-swizzled (8 chunks of 16B per row,
  // physical chunk = row*8 + (j ^ (row&7))) -> async-ld16-compatible AND
  // conflict-free fragment reads. Total LDS = 40960 B -> 4 blocks/CU.
  __shared__ bf16 Ks[2][64 * 64];
  __shared__ bf16 Vs[2][64 * 64];
  __shared__ bf16 Ps[64 * 64];

  const int bh = blockIdx.y;
  const int b = bh >> 4, h = bh & 15;
  const int qt0 = blockIdx.x * 64;
  const int tid = threadIdx.x;
  const int wave = tid >> 6, lane = tid & 63;
  const int col = lane & 15, quad = lane >> 4;
  const int len = lengths[b];
  const int nkt = (len + 63) >> 6;

  // Q fragments in registers (B-operand layout), loop-invariant
  const bf16* qptr = Qd + ((size_t)bh * 2048 + qt0 + wave * 16 + col) * 64 + quad * 8;
  const s16x8 bq0 = *(const s16x8*)(qptr);
  const s16x8 bq1 = *(const s16x8*)(qptr + 32);

  const bf16* Kg = Kd + (size_t)bh * 2048 * 64;
  const bf16* Vg = Vt + (size_t)bh * 64 * 2048;

  // async stage of K & V^T 64x64 tiles, chunk-swizzled
  auto stage = [&](int kt, int bufsel) {
    const int s0 = kt * 64;
#pragma unroll
    for (int rep = 0; rep < 2; rep++) {
      int c = wave * 128 + rep * 64 + lane;
      int row = c >> 3, j = (c & 7) ^ (row & 7);
      async_ld16(Kg + (size_t)(s0 + row) * 64 + j * 8,
                 (char*)&Ks[bufsel][0] + (size_t)(wave * 128 + rep * 64) * 16);
      async_ld16(Vg + (size_t)row * 2048 + s0 + j * 8,
                 (char*)&Vs[bufsel][0] + (size_t)(wave * 128 + rep * 64) * 16);
    }
  };

  float m_run = -1e30f, l_run = 0.f;
  f32x4 oacc[4];
#pragma unroll
  for (int dt = 0; dt < 4; dt++) oacc[dt] = (f32x4){0.f, 0.f, 0.f, 0.f};

  stage(0, 0);
  __syncthreads();

  for (int kt = 0; kt < nkt; kt++) {
    const int bufsel = kt & 1;
    if (kt + 1 < nkt) stage(kt + 1, bufsel ^ 1);
    const bf16* Kb = &Ks[bufsel][0];
    const bf16* Vb = &Vs[bufsel][0];
    const int s0 = kt * 64;

    // S^T: 4 tiles of 16 s x 16 q
    f32x4 sacc[4];
#pragma unroll
    for (int ti = 0; ti < 4; ti++) sacc[ti] = (f32x4){0.f, 0.f, 0.f, 0.f};
#pragma unroll
    for (int kh = 0; kh < 2; kh++) {
      const s16x8 bq = kh ? bq1 : bq0;
#pragma unroll
      for (int ti = 0; ti < 4; ti++) {
        int row = ti * 16 + col;
        int j = (kh * 4 + quad) ^ (row & 7);
        const s16x8 ak = *(const s16x8*)(Kb + ((row << 3) + j) * 8);
        sacc[ti] = __builtin_amdgcn_mfma_f32_16x16x32_bf16(ak, bq, sacc[ti], 0, 0, 0);
      }
    }

    // mask only the straddling last tile
    if (s0 + 64 > len) {
#pragma unroll
      for (int ti = 0; ti < 4; ti++)
#pragma unroll
        for (int r = 0; r < 4; r++)
          if (s0 + ti * 16 + quad * 4 + r >= len) sacc[ti][r] = -1e30f;
    }

    // online softmax, base-2 domain; lane's 16 values all belong to q = col
    float mx = -1e30f;
#pragma unroll
    for (int ti = 0; ti < 4; ti++)
#pragma unroll
      for (int r = 0; r < 4; r++) mx = fmaxf(mx, sacc[ti][r]);
    mx = fmaxf(mx, __shfl_xor(mx, 16, 64));
    mx = fmaxf(mx, __shfl_xor(mx, 32, 64));
    const float m_new = fmaxf(m_run, mx);
    const float alpha = exp2f(m_run - m_new);
    m_run = m_new;
    float sum = 0.f;
#pragma unroll
    for (int ti = 0; ti < 4; ti++)
#pragma unroll
      for (int r = 0; r < 4; r++) {
        float p = exp2f(sacc[ti][r] - m_new);
        sacc[ti][r] = p;
        sum += p;
      }
    sum += __shfl_xor(sum, 16, 64);
    sum += __shfl_xor(sum, 32, 64);
    l_run = l_run * alpha + sum;

    // broadcast alpha from column-state lanes to O-row layout, rescale O
    float al[4];
#pragma unroll
    for (int r = 0; r < 4; r++) al[r] = __shfl(alpha, quad * 4 + r, 64);
#pragma unroll
    for (int dt = 0; dt < 4; dt++)
#pragma unroll
      for (int r = 0; r < 4; r++) oacc[dt][r] *= al[r];

    // P -> LDS, b64 per tile (4 consecutive s), swizzled [q-row][s] layout
    const int prow = wave * 16 + col;
#pragma unroll
    for (int ti = 0; ti < 4; ti++) {
      union { bf16 hv[4]; uint2 u2; } pk;
#pragma unroll
      for (int r = 0; r < 4; r++) pk.hv[r] = __float2bfloat16(sacc[ti][r]);
      int jw = (ti * 2 + (quad >> 1)) ^ (col & 7);
      *(uint2*)((char*)Ps + prow * 128 + (jw << 4) + ((quad & 1) << 3)) = pk.u2;
    }

    // O += P V : A = P rows (q), B = V^T rows (d)
#pragma unroll
    for (int sk = 0; sk < 2; sk++) {
      int jr = sk * 4 + quad;
      const s16x8 ap = *(const s16x8*)((char*)Ps + prow * 128 + ((jr ^ (col & 7)) << 4));
#pragma unroll
      for (int dt = 0; dt < 4; dt++) {
        int vrow = dt * 16 + col;
        const s16x8 bv = *(const s16x8*)(Vb + ((vrow << 3) + (jr ^ (vrow & 7))) * 8);
        oacc[dt] = __builtin_amdgcn_mfma_f32_16x16x32_bf16(ap, bv, oacc[dt], 0, 0, 0);
      }
    }
    __syncthreads();
  }

  // epilogue: O / l -> attn_out[(t*2+b)*1024 + h*64 + d]
  float lo[4];
#pragma unroll
  for (int r = 0; r < 4; r++) lo[r] = 1.f / __shfl(l_run, quad * 4 + r, 64);
#pragma unroll
  for (int dt = 0; dt < 4; dt++)
#pragma unroll
    for (int r = 0; r < 4; r++) {
      int t = qt0 + wave * 16 + quad * 4 + r;
      attn_out[((size_t)t * 2 + b) * 1024 + h * 64 + dt * 16 + col] =
          __float2bfloat16(oacc[dt][r] * lo[r]);
    }
}

// ---------------- output projection: [4096,1024] @ [1024,1024]^T + b_out (fp32 out) --------
__global__ __launch_bounds__(256) void gemm_out(const bf16* __restrict__ Aa,
                                                const bf16* __restrict__ W,
                                                const float* __restrict__ bias,
                                                float* __restrict__ out) {
  __shared__ bf16 As[128 * 32];
  __shared__ bf16 Bs[128 * 32];
  const int m0 = blockIdx.y * 128, n0 = blockIdx.x * 128;
  f32x4 acc[4][4];
  gemm_mainloop(Aa, W, As, Bs, m0, n0, acc);
  const int tid = threadIdx.x;
  const int wave = tid >> 6, lane = tid & 63;
  const int col = lane & 15, quad = lane >> 4;
  const int wm = wave & 1, wn = wave >> 1;
#pragma unroll
  for (int mi = 0; mi < 4; mi++)
#pragma unroll
    for (int ni = 0; ni < 4; ni++)
#pragma unroll
      for (int r = 0; r < 4; r++) {
        int m = m0 + wm * 64 + mi * 16 + quad * 4 + r;
        int n = n0 + wn * 64 + ni * 16 + col;
        out[(size_t)m * 1024 + n] = acc[mi][ni][r] + bias[n];
      }
}

// ---------------- launch ----------------
extern "C" void kernel_launch(void* const* d_in, const int* in_sizes, int n_in,
                              void* d_out, int out_size, void* d_ws, size_t ws_size,
                              hipStream_t stream) {
  (void)in_sizes; (void)n_in; (void)out_size; (void)ws_size;
  const float* query = (const float*)d_in[0];
  const void*  mask  = d_in[1];
  const float* W_in  = (const float*)d_in[2];
  const float* b_in  = (const float*)d_in[3];
  const float* W_out = (const float*)d_in[4];
  const float* b_out = (const float*)d_in[5];
  float* out = (float*)d_out;

  char* ws = (char*)d_ws;
  bf16* Xbf    = (bf16*)(ws);                       // 8 MB  [4096][1024]
  bf16* attnb  = (bf16*)(ws);                       // alias (dead Xbf)
  bf16* Winbf  = (bf16*)(ws + 8388608);             // 6 MB  [3072][1024]
  bf16* Woutbf = (bf16*)(ws + 8388608);             // alias (dead Winbf), 2 MB
  bf16* Qd     = (bf16*)(ws + 14680064);            // 8 MB  [32][2048][64]
  bf16* Kd     = (bf16*)(ws + 23068672);            // 8 MB  [32][2048][64]
  bf16* Vt     = (bf16*)(ws + 31457280);            // 8 MB  [32][64][2048]
  int*  lens   = (int*)(ws + 39845888);

  lengths_kernel<<<2, 256, 0, stream>>>(mask, lens);
  f32_to_bf16_kernel<<<2048, 256, 0, stream>>>(query, Xbf, 4194304);
  f32_to_bf16_kernel<<<1536, 256, 0, stream>>>(W_in, Winbf, 3145728);
  gemm_qkv<<<dim3(24, 32), 256, 0, stream>>>(Xbf, Winbf, b_in, Qd, Kd, Vt);
  f32_to_bf16_kernel<<<512, 256, 0, stream>>>(W_out, Woutbf, 1048576);
  attn_kernel<<<dim3(32, 32), 256, 0, stream>>>(Qd, Kd, Vt, lens, attnb);
  gemm_out<<<dim3(8, 32), 256, 0, stream>>>(attnb, Woutbf, b_out, out);
}